// Round 7
// baseline (884.971 us; speedup 1.0000x reference)
//
#include <hip/hip_runtime.h>
#include <math.h>

// Problem constants
#define B_ 8
#define C_ 256
#define H_ 56
#define W_ 56
#define N_ 3136  // 56*56 = 49*64
#define BN_ (B_*N_)

typedef __attribute__((ext_vector_type(8))) short short8;
typedef __attribute__((ext_vector_type(4))) float f32x4;
typedef __attribute__((ext_vector_type(16))) float f32x16;
typedef __attribute__((ext_vector_type(4))) unsigned short u16x4;
#define MFMA16(A, Bf, Cf) __builtin_amdgcn_mfma_f32_16x16x32_bf16((A), (Bf), (Cf), 0, 0, 0)
#define MFMA32(A, Bf, Cf) __builtin_amdgcn_mfma_f32_32x32x16_bf16((A), (Bf), (Cf), 0, 0, 0)

// -------------------- workspace layout (ushort units) --------------------
// xhi/xlo: padded pixel-major x during conv; REUSED as O-partials for flash.
// Ahi/Alo: conv weights; first 200KB of Ahi REUSED as flash m/l arrays.
#define XT_ELEMS (B_*58*64*256)           // 7,602,176
#define A_ELEMS  (320*2304)               // 737,280
#define AHI_OFF  (2*XT_ELEMS)
#define ALO_OFF  (AHI_OFF + A_ELEMS)
#define QKT_HI_OFF (ALO_OFF + A_ELEMS)
#define QKT_ELEMS  (B_*N_*64)             // 1,605,632
#define QKT_LO_OFF (QKT_HI_OFF + QKT_ELEMS)
#define VBF_OFF    (QKT_LO_OFF + QKT_ELEMS)
#define VBF_ELEMS  (B_*C_*N_)             // 6,422,528

// LDS swizzle for conv B-slabs: chunk (r,col,c8) -> uint4 index
#define SWZ(r, col, c8) ((((r)*64 + (col))*4) + ((c8) ^ ((col) & 3)))

// P LDS row stride (ushorts)
#define PSTR 76

__device__ inline unsigned short f2bf(float f) {
    unsigned u = __float_as_uint(f);
    unsigned r = (u + 0x7fffu + ((u >> 16) & 1u)) >> 16;   // RNE
    return (unsigned short)r;
}
__device__ inline float bf2f(unsigned short h) {
    return __uint_as_float(((unsigned)h) << 16);
}

// ---------------------------------------------------------------------------
// Kernel 0: zero the padded x regions.
// ---------------------------------------------------------------------------
__global__ __launch_bounds__(256) void zero_pads(uint4* __restrict__ p, int n16)
{
    const int stride = gridDim.x * 256;
    for (int i = blockIdx.x * 256 + threadIdx.x; i < n16; i += stride)
        p[i] = make_uint4(0, 0, 0, 0);
}

// ---------------------------------------------------------------------------
// Kernel 1a: x (fp32 NCHW) -> padded pixel-major bf16 hi/lo.
// ---------------------------------------------------------------------------
__global__ __launch_bounds__(256) void prep_x(
    const float* __restrict__ x,
    unsigned short* __restrict__ xhi, unsigned short* __restrict__ xlo)
{
    __shared__ float xs[64][57];
    const int cc = blockIdx.x, y = blockIdx.y, b = blockIdx.z;
    const int t = threadIdx.x;
    const int c0 = cc * 64;
    for (int idx = t; idx < 64 * 56; idx += 256) {
        const int ch = idx / 56, xc = idx - ch * 56;
        xs[ch][xc] = x[((size_t)(b*C_ + c0 + ch)*H_ + y)*W_ + xc];
    }
    __syncthreads();
    for (int idx = t; idx < 56 * 32; idx += 256) {
        const int xc = idx >> 5, chp = idx & 31;
        const float v0 = xs[2*chp][xc], v1 = xs[2*chp + 1][xc];
        const unsigned short h0 = f2bf(v0), h1 = f2bf(v1);
        const unsigned short l0 = f2bf(v0 - bf2f(h0));
        const unsigned short l1 = f2bf(v1 - bf2f(h1));
        const size_t o = ((size_t)(b*58 + y + 1) * 64 + (xc + 1)) * 256 + c0 + 2*chp;
        *(unsigned*)(xhi + o) = (unsigned)h0 | ((unsigned)h1 << 16);
        *(unsigned*)(xlo + o) = (unsigned)l0 | ((unsigned)l1 << 16);
    }
}

// ---------------------------------------------------------------------------
// Kernel 1b: weights -> A_hi/A_lo [320][2304], k = s*256 + c.
// ---------------------------------------------------------------------------
__global__ __launch_bounds__(256) void prep_w(
    const float* __restrict__ wq, const float* __restrict__ wk,
    const float* __restrict__ wv,
    unsigned short* __restrict__ Ahi, unsigned short* __restrict__ Alo)
{
    const int g = blockIdx.x * 256 + threadIdx.x;
    if (g >= 320 * 2304) return;
    const int m = g / 2304, k = g - m * 2304;
    const int s = k >> 8, c = k & 255;
    float w;
    if (m < 32)      w = wq[((size_t)m*C_ + c)*9 + s];
    else if (m < 64) w = wk[((size_t)(m-32)*C_ + c)*9 + s];
    else             w = wv[((size_t)(m-64)*C_ + c)*9 + s];
    const unsigned short h = f2bf(w);
    Ahi[g] = h;
    Alo[g] = f2bf(w - bf2f(h));
}

// ---------------------------------------------------------------------------
// Kernel 2a: q/k conv (bf16x3). grid (b 8, y 56), block 256 = 4 waves.
// Block: m = 64 qk rows, n = one y-row (64 px). Wave w: 16 m-rows x 64 px.
// LDS: 3 padded x rows (hi+lo), register-prefetch next c-chunk.
// ---------------------------------------------------------------------------
__global__ __launch_bounds__(256) void conv_qk2(
    const unsigned short* __restrict__ xhi, const unsigned short* __restrict__ xlo,
    const unsigned short* __restrict__ Ahi, const unsigned short* __restrict__ Alo,
    const float* __restrict__ bq, const float* __restrict__ bk,
    unsigned short* __restrict__ qkt_hi, unsigned short* __restrict__ qkt_lo)
{
    __shared__ uint4 sH[3*64*4 + 8];   // +8 pad: col+dx can run to 65 (px>=56 discarded)
    __shared__ uint4 sL[3*64*4 + 8];
    const int b = blockIdx.x, y = blockIdx.y;
    const int t = threadIdx.x;
    const int w = t >> 6, L = t & 63;
    const int ln = L & 15, quad = L >> 4;

    f32x4 acc[4];
#pragma unroll
    for (int nt = 0; nt < 4; nt++) acc[nt] = (f32x4)0.0f;

    uint4 ph[3], pl[3];
#pragma unroll
    for (int i = 0; i < 3; i++) {
        const int idx = t + i*256;
        const int r = idx >> 8, col = (idx >> 2) & 63, c8 = idx & 3;
        const size_t go = ((size_t)((b*58 + y + r)*64 + col))*256 + c8*8;
        ph[i] = *(const uint4*)(xhi + go);
        pl[i] = *(const uint4*)(xlo + go);
    }

    for (int cc = 0; cc < 8; cc++) {
        __syncthreads();
#pragma unroll
        for (int i = 0; i < 3; i++) {
            const int idx = t + i*256;
            const int r = idx >> 8, col = (idx >> 2) & 63, c8 = idx & 3;
            sH[SWZ(r, col, c8)] = ph[i];
            sL[SWZ(r, col, c8)] = pl[i];
        }
        __syncthreads();
        if (cc < 7) {
#pragma unroll
            for (int i = 0; i < 3; i++) {
                const int idx = t + i*256;
                const int r = idx >> 8, col = (idx >> 2) & 63, c8 = idx & 3;
                const size_t go = ((size_t)((b*58 + y + r)*64 + col))*256 + (cc+1)*32 + c8*8;
                ph[i] = *(const uint4*)(xhi + go);
                pl[i] = *(const uint4*)(xlo + go);
            }
        }
#pragma unroll
        for (int s = 0; s < 9; s++) {
            const int dy = s / 3 - 1, dx = s % 3 - 1;
            const size_t aoff = (size_t)(w*16 + ln)*2304 + s*256 + cc*32 + quad*8;
            const short8 ah = *(const short8*)(Ahi + aoff);
            const short8 al = *(const short8*)(Alo + aoff);
            const int r = dy + 1;
#pragma unroll
            for (int nt = 0; nt < 4; nt++) {
                const int col = nt*16 + ln + dx + 1;
                const int i4 = SWZ(r, col, quad);
                const short8 bh = *(const short8*)&sH[i4];
                const short8 bl = *(const short8*)&sL[i4];
                acc[nt] = MFMA16(ah, bh, acc[nt]);
                acc[nt] = MFMA16(ah, bl, acc[nt]);
                acc[nt] = MFMA16(al, bh, acc[nt]);
            }
        }
    }

    // epilogue: C/D col = ln (px), row = quad*4 + r (m-row within wave's 16)
#pragma unroll
    for (int nt = 0; nt < 4; nt++) {
        const int px = nt*16 + ln;
        if (px >= 56) continue;
        const int pix = y*56 + px;
        u16x4 hi4, lo4;
#pragma unroll
        for (int r = 0; r < 4; r++) {
            const int m = w*16 + quad*4 + r;
            const float bias = (m < 32) ? bq[m] : bk[m - 32];
            const float val = acc[nt][r] + bias;
            const unsigned short h = f2bf(val);
            hi4[r] = h;
            lo4[r] = f2bf(val - bf2f(h));
        }
        const size_t o = (size_t)(b*N_ + pix)*64 + w*16 + quad*4;
        *(u16x4*)(qkt_hi + o) = hi4;
        *(u16x4*)(qkt_lo + o) = lo4;
    }
}

// ---------------------------------------------------------------------------
// Kernel 2b: v conv (plain bf16). grid (b 8, y 56, mg 4), block 256 = 4 waves.
// Block: m = 64 v channels, n = one y-row. Wave w: 16 ch x 64 px.
// ---------------------------------------------------------------------------
__global__ __launch_bounds__(256) void conv_v2(
    const unsigned short* __restrict__ xhi,
    const unsigned short* __restrict__ Ahi,
    const float* __restrict__ bv,
    unsigned short* __restrict__ vbf)
{
    __shared__ uint4 sH[3*64*4 + 8];
    const int b = blockIdx.x, y = blockIdx.y, mg = blockIdx.z;
    const int t = threadIdx.x;
    const int w = t >> 6, L = t & 63;
    const int ln = L & 15, quad = L >> 4;
    const int m0 = 64 + mg*64 + w*16;   // A row base (v rows start at 64)

    f32x4 acc[4];
#pragma unroll
    for (int nt = 0; nt < 4; nt++) acc[nt] = (f32x4)0.0f;

    uint4 ph[3];
#pragma unroll
    for (int i = 0; i < 3; i++) {
        const int idx = t + i*256;
        const int r = idx >> 8, col = (idx >> 2) & 63, c8 = idx & 3;
        const size_t go = ((size_t)((b*58 + y + r)*64 + col))*256 + c8*8;
        ph[i] = *(const uint4*)(xhi + go);
    }

    for (int cc = 0; cc < 8; cc++) {
        __syncthreads();
#pragma unroll
        for (int i = 0; i < 3; i++) {
            const int idx = t + i*256;
            const int r = idx >> 8, col = (idx >> 2) & 63, c8 = idx & 3;
            sH[SWZ(r, col, c8)] = ph[i];
        }
        __syncthreads();
        if (cc < 7) {
#pragma unroll
            for (int i = 0; i < 3; i++) {
                const int idx = t + i*256;
                const int r = idx >> 8, col = (idx >> 2) & 63, c8 = idx & 3;
                const size_t go = ((size_t)((b*58 + y + r)*64 + col))*256 + (cc+1)*32 + c8*8;
                ph[i] = *(const uint4*)(xhi + go);
            }
        }
#pragma unroll
        for (int s = 0; s < 9; s++) {
            const int dy = s / 3 - 1, dx = s % 3 - 1;
            const size_t aoff = (size_t)(m0 + ln)*2304 + s*256 + cc*32 + quad*8;
            const short8 a = *(const short8*)(Ahi + aoff);
            const int r = dy + 1;
#pragma unroll
            for (int nt = 0; nt < 4; nt++) {
                const int col = nt*16 + ln + dx + 1;
                const short8 bf = *(const short8*)&sH[SWZ(r, col, quad)];
                acc[nt] = MFMA16(a, bf, acc[nt]);
            }
        }
    }

    // epilogue: v channel c = mg*64 + w*16 + quad*4 + r
#pragma unroll
    for (int nt = 0; nt < 4; nt++) {
        const int px = nt*16 + ln;
        if (px >= 56) continue;
        const int pix = y*56 + px;
#pragma unroll
        for (int r = 0; r < 4; r++) {
            const int c = mg*64 + w*16 + quad*4 + r;
            vbf[(size_t)(b*C_ + c)*N_ + pix] = f2bf(acc[nt][r] + bv[c]);
        }
    }
}

// ---------------------------------------------------------------------------
// Kernel 3: fused flash attention, j-split. grid (392, chalf 2, jh 2),
// block 256 = 4 waves. Writes UNNORMALIZED O-partials (bf16) + per-row m,l.
// Wave w: S^T for i-rows [it*64+w*16,+16) over j-half (per-lane stats);
// PV for c-slice chalf*128 + w*32, both 32-i tiles. 1 barrier per jt.
// ---------------------------------------------------------------------------
__global__ __launch_bounds__(256, 6) void attn_flash3(
    const unsigned short* __restrict__ qkt_hi, const unsigned short* __restrict__ qkt_lo,
    const unsigned short* __restrict__ vbf,
    unsigned short* __restrict__ op0, unsigned short* __restrict__ op1,
    float* __restrict__ mlbase)
{
    __shared__ unsigned short P[2][64*PSTR];   // 19.0 KB
    __shared__ float alphaL[2][64];

    const int bx = blockIdx.x;
    const int b = bx & 7, it = bx >> 3;
    const int chalf = blockIdx.y;
    const int jh = blockIdx.z;
    const int jt0 = jh * 25, njt = 25 - jh;   // 25 / 24 tiles
    const int i_base = it * 64;
    const int t = threadIdx.x;
    const int w = t >> 6, L = t & 63;
    const int ln = L & 15, quad = L >> 4;
    const int l32 = L & 31, h32 = L >> 5;

    const size_t qoff = (size_t)(b*N_ + i_base + w*16 + ln)*64 + quad*8;
    const short8 qh = *(const short8*)(qkt_hi + qoff);
    const short8 ql = *(const short8*)(qkt_lo + qoff);

    float m_run = -INFINITY, l_run = 0.0f;
    f32x16 O0 = (f32x16)0.0f, O1 = (f32x16)0.0f;
    const unsigned short* vrow = vbf + (size_t)(b*C_ + chalf*128 + w*32 + l32) * N_;

    for (int jtl = 0; jtl < njt; jtl++) {
        const int jt = jt0 + jtl;
        const int buf = jtl & 1;

        // ---- V prefetch first (addresses independent of everything) ----
        short8 Va[4];
#pragma unroll
        for (int s = 0; s < 4; s++)
            Va[s] = *(const short8*)(vrow + jt*64 + s*16 + h32*8);

        // ---- S^T phase ----
        f32x4 sacc[4];
#pragma unroll
        for (int tj = 0; tj < 4; tj++) {
            const size_t koff = (size_t)(b*N_ + jt*64 + tj*16 + ln)*64 + 32 + quad*8;
            const short8 kh = *(const short8*)(qkt_hi + koff);
            const short8 kl = *(const short8*)(qkt_lo + koff);
            f32x4 a = (f32x4)0.0f;
            a = MFMA16(kh, qh, a);
            a = MFMA16(kh, ql, a);
            a = MFMA16(kl, qh, a);
            sacc[tj] = a;
        }
        // ---- stats: depth-4 max tree + 2 shuffles ----
        float mt0 = fmaxf(fmaxf(sacc[0][0], sacc[0][1]), fmaxf(sacc[0][2], sacc[0][3]));
        float mt1 = fmaxf(fmaxf(sacc[1][0], sacc[1][1]), fmaxf(sacc[1][2], sacc[1][3]));
        float mt2 = fmaxf(fmaxf(sacc[2][0], sacc[2][1]), fmaxf(sacc[2][2], sacc[2][3]));
        float mt3 = fmaxf(fmaxf(sacc[3][0], sacc[3][1]), fmaxf(sacc[3][2], sacc[3][3]));
        float mx = fmaxf(fmaxf(mt0, mt1), fmaxf(mt2, mt3));
        mx = fmaxf(mx, __shfl_xor(mx, 16));
        mx = fmaxf(mx, __shfl_xor(mx, 32));
        const float m_new = fmaxf(m_run, mx);
        const float alpha = __expf(m_run - m_new);
        m_run = m_new;

        float p[4][4];
#pragma unroll
        for (int tj = 0; tj < 4; tj++)
#pragma unroll
            for (int r = 0; r < 4; r++)
                p[tj][r] = __expf(sacc[tj][r] - m_new);
        float s0 = (p[0][0] + p[0][1]) + (p[0][2] + p[0][3]);
        float s1 = (p[1][0] + p[1][1]) + (p[1][2] + p[1][3]);
        float s2 = (p[2][0] + p[2][1]) + (p[2][2] + p[2][3]);
        float s3 = (p[3][0] + p[3][1]) + (p[3][2] + p[3][3]);
        float ps = (s0 + s1) + (s2 + s3);
        ps += __shfl_xor(ps, 16);
        ps += __shfl_xor(ps, 32);
        l_run = l_run * alpha + ps;

        {
            unsigned short* prow = &P[buf][(w*16 + ln)*PSTR];
#pragma unroll
            for (int tj = 0; tj < 4; tj++) {
                u16x4 pk;
#pragma unroll
                for (int r = 0; r < 4; r++) pk[r] = f2bf(p[tj][r]);
                *(u16x4*)(prow + tj*16 + quad*4) = pk;
            }
        }
        if (quad == 0) alphaL[buf][w*16 + ln] = alpha;

        __syncthreads();   // P[buf] + alphaL[buf] ready

        // ---- PV phase ----
        const float a0 = alphaL[buf][l32];
        const float a1 = alphaL[buf][32 + l32];
        if (__any(a0 != 1.0f || a1 != 1.0f)) {
#pragma unroll
            for (int rg = 0; rg < 16; rg++) { O0[rg] *= a0; O1[rg] *= a1; }
        }
#pragma unroll
        for (int s = 0; s < 4; s++) {
            const short8 B0 = *(const short8*)&P[buf][l32*PSTR + s*16 + h32*8];
            const short8 B1 = *(const short8*)&P[buf][(32 + l32)*PSTR + s*16 + h32*8];
            O0 = MFMA32(Va[s], B0, O0);
            O1 = MFMA32(Va[s], B1, O1);
        }
    }

    // ---- epilogue: raw partials ----
    if (chalf == 0 && quad == 0) {
        const int i = i_base + w*16 + ln;
        mlbase[jh*BN_ + b*N_ + i]       = m_run;
        mlbase[(2 + jh)*BN_ + b*N_ + i] = l_run;
    }
    unsigned short* OP = jh ? op1 : op0;
#pragma unroll
    for (int itile = 0; itile < 2; itile++) {
        const f32x16 Ot = itile ? O1 : O0;
        const int pix = i_base + itile*32 + l32;
#pragma unroll
        for (int reg = 0; reg < 16; reg++) {
            const int c = chalf*128 + w*32 + (reg & 3) + 8*(reg >> 2) + 4*h32;
            OP[(size_t)(b*C_ + c)*N_ + pix] = f2bf(Ot[reg]);
        }
    }
}

// ---------------------------------------------------------------------------
// Kernel 4: combine the two j-half partials + residual.
// grid (392 = b*49, ch2 2), block 256: lane = pix offset (64), t>>6 = c offset.
// ---------------------------------------------------------------------------
__global__ __launch_bounds__(256) void combine(
    const unsigned short* __restrict__ op0, const unsigned short* __restrict__ op1,
    const float* __restrict__ mlbase,
    const float* __restrict__ x, const float* __restrict__ gptr,
    float* __restrict__ out)
{
    const int bid = blockIdx.x;
    const int b = bid / 49, pt = bid - b*49;
    const int ch2 = blockIdx.y;
    const int t = threadIdx.x;
    const int pix = pt*64 + (t & 63);
    const int cofs = t >> 6;

    const float m0 = mlbase[b*N_ + pix];
    const float m1 = mlbase[BN_ + b*N_ + pix];
    const float l0 = mlbase[2*BN_ + b*N_ + pix];
    const float l1 = mlbase[3*BN_ + b*N_ + pix];
    const float mm = fmaxf(m0, m1);
    const float a0 = __expf(m0 - mm), a1 = __expf(m1 - mm);
    const float gamma = gptr[0];
    const float inv = gamma / (a0*l0 + a1*l1);
    const float c0 = a0 * inv, c1 = a1 * inv;

    for (int ci = 0; ci < 32; ci++) {
        const int c = ch2*128 + cofs + ci*4;
        const size_t idx = (size_t)(b*C_ + c)*N_ + pix;
        const float o = c0 * bf2f(op0[idx]) + c1 * bf2f(op1[idx]);
        out[idx] = fmaf(1.0f, x[idx], o);
    }
}

// ---------------------------------------------------------------------------
extern "C" void kernel_launch(void* const* d_in, const int* in_sizes, int n_in,
                              void* d_out, int out_size, void* d_ws, size_t ws_size,
                              hipStream_t stream)
{
    (void)in_sizes; (void)n_in; (void)out_size; (void)ws_size;
    const float* x  = (const float*)d_in[0];
    const float* wq = (const float*)d_in[1];
    const float* bq = (const float*)d_in[2];
    const float* wk = (const float*)d_in[3];
    const float* bk = (const float*)d_in[4];
    const float* wv = (const float*)d_in[5];
    const float* bv = (const float*)d_in[6];
    const float* gm = (const float*)d_in[7];
    float* out = (float*)d_out;

    unsigned short* u = (unsigned short*)d_ws;
    unsigned short* xhi = u;                      // conv input; later O-partial jh=0
    unsigned short* xlo = u + XT_ELEMS;           // conv input; later O-partial jh=1
    unsigned short* Ahi = u + AHI_OFF;            // weights; first 200KB later m/l
    unsigned short* Alo = u + ALO_OFF;
    unsigned short* qkt_hi = u + QKT_HI_OFF;
    unsigned short* qkt_lo = u + QKT_LO_OFF;
    unsigned short* vbf = u + VBF_OFF;
    float* mlbase = (float*)Ahi;                  // 4 * B*N floats = 401 KB

    hipLaunchKernelGGL(zero_pads, dim3(1024), dim3(256), 0, stream,
                       (uint4*)d_ws, (2*XT_ELEMS*2)/16);
    hipLaunchKernelGGL(prep_x, dim3(4, 56, 8), dim3(256), 0, stream, x, xhi, xlo);
    hipLaunchKernelGGL(prep_w, dim3(2880), dim3(256), 0, stream, wq, wk, wv, Ahi, Alo);
    hipLaunchKernelGGL(conv_qk2, dim3(8, 56), dim3(256), 0, stream,
                       xhi, xlo, Ahi, Alo, bq, bk, qkt_hi, qkt_lo);
    hipLaunchKernelGGL(conv_v2, dim3(8, 56, 4), dim3(256), 0, stream,
                       xhi, Ahi, bv, vbf);
    hipLaunchKernelGGL(attn_flash3, dim3(49*8, 2, 2), dim3(256), 0, stream,
                       qkt_hi, qkt_lo, vbf, xhi, xlo, mlbase);
    hipLaunchKernelGGL(combine, dim3(392, 2), dim3(256), 0, stream,
                       xhi, xlo, mlbase, x, gm, out);
}

// Round 8
// 548.404 us; speedup vs baseline: 1.6137x; 1.6137x over previous
//
#include <hip/hip_runtime.h>
#include <math.h>

// Problem constants
#define B_ 8
#define C_ 256
#define H_ 56
#define W_ 56
#define N_ 3136  // 56*56 = 49*64
#define BN_ (B_*N_)

typedef __attribute__((ext_vector_type(8))) short short8;
typedef __attribute__((ext_vector_type(4))) float f32x4;
typedef __attribute__((ext_vector_type(16))) float f32x16;
typedef __attribute__((ext_vector_type(4))) unsigned short u16x4;
#define MFMA16(A, Bf, Cf) __builtin_amdgcn_mfma_f32_16x16x32_bf16((A), (Bf), (Cf), 0, 0, 0)
#define MFMA32(A, Bf, Cf) __builtin_amdgcn_mfma_f32_32x32x16_bf16((A), (Bf), (Cf), 0, 0, 0)

// -------------------- workspace layout (ushort units) --------------------
// xhi/xlo: padded pixel-major x during conv; REUSED as O-partials for flash.
// Ahi/Alo: conv weights; first 400KB of Ahi REUSED as flash m/l arrays.
#define XT_ELEMS (B_*58*64*256)           // 7,602,176
#define A_ELEMS  (320*2304)               // 737,280
#define AHI_OFF  (2*XT_ELEMS)
#define ALO_OFF  (AHI_OFF + A_ELEMS)
#define QKT_HI_OFF (ALO_OFF + A_ELEMS)
#define QKT_ELEMS  (B_*N_*64)             // 1,605,632
#define QKT_LO_OFF (QKT_HI_OFF + QKT_ELEMS)
#define VBF_OFF    (QKT_LO_OFF + QKT_ELEMS)
#define VBF_ELEMS  (B_*C_*N_)             // 6,422,528

// LDS swizzle for conv B-slabs: chunk (r,col,c8) -> uint4 index
#define SWZ(r, col, c8) ((((r)*64 + (col))*4) + ((c8) ^ ((col) & 3)))

// P LDS row stride (ushorts)
#define PSTR 76

__device__ inline unsigned short f2bf(float f) {
    unsigned u = __float_as_uint(f);
    unsigned r = (u + 0x7fffu + ((u >> 16) & 1u)) >> 16;   // RNE
    return (unsigned short)r;
}
__device__ inline float bf2f(unsigned short h) {
    return __uint_as_float(((unsigned)h) << 16);
}

// ---------------------------------------------------------------------------
// Kernel 0: zero the padded x regions.
// ---------------------------------------------------------------------------
__global__ __launch_bounds__(256) void zero_pads(uint4* __restrict__ p, int n16)
{
    const int stride = gridDim.x * 256;
    for (int i = blockIdx.x * 256 + threadIdx.x; i < n16; i += stride)
        p[i] = make_uint4(0, 0, 0, 0);
}

// ---------------------------------------------------------------------------
// Kernel 1a: x (fp32 NCHW) -> padded pixel-major bf16 hi/lo.
// ---------------------------------------------------------------------------
__global__ __launch_bounds__(256) void prep_x(
    const float* __restrict__ x,
    unsigned short* __restrict__ xhi, unsigned short* __restrict__ xlo)
{
    __shared__ float xs[64][57];
    const int cc = blockIdx.x, y = blockIdx.y, b = blockIdx.z;
    const int t = threadIdx.x;
    const int c0 = cc * 64;
    for (int idx = t; idx < 64 * 56; idx += 256) {
        const int ch = idx / 56, xc = idx - ch * 56;
        xs[ch][xc] = x[((size_t)(b*C_ + c0 + ch)*H_ + y)*W_ + xc];
    }
    __syncthreads();
    for (int idx = t; idx < 56 * 32; idx += 256) {
        const int xc = idx >> 5, chp = idx & 31;
        const float v0 = xs[2*chp][xc], v1 = xs[2*chp + 1][xc];
        const unsigned short h0 = f2bf(v0), h1 = f2bf(v1);
        const unsigned short l0 = f2bf(v0 - bf2f(h0));
        const unsigned short l1 = f2bf(v1 - bf2f(h1));
        const size_t o = ((size_t)(b*58 + y + 1) * 64 + (xc + 1)) * 256 + c0 + 2*chp;
        *(unsigned*)(xhi + o) = (unsigned)h0 | ((unsigned)h1 << 16);
        *(unsigned*)(xlo + o) = (unsigned)l0 | ((unsigned)l1 << 16);
    }
}

// ---------------------------------------------------------------------------
// Kernel 1b: weights -> A_hi/A_lo [320][2304], k = s*256 + c.
// ---------------------------------------------------------------------------
__global__ __launch_bounds__(256) void prep_w(
    const float* __restrict__ wq, const float* __restrict__ wk,
    const float* __restrict__ wv,
    unsigned short* __restrict__ Ahi, unsigned short* __restrict__ Alo)
{
    const int g = blockIdx.x * 256 + threadIdx.x;
    if (g >= 320 * 2304) return;
    const int m = g / 2304, k = g - m * 2304;
    const int s = k >> 8, c = k & 255;
    float w;
    if (m < 32)      w = wq[((size_t)m*C_ + c)*9 + s];
    else if (m < 64) w = wk[((size_t)(m-32)*C_ + c)*9 + s];
    else             w = wv[((size_t)(m-64)*C_ + c)*9 + s];
    const unsigned short h = f2bf(w);
    Ahi[g] = h;
    Alo[g] = f2bf(w - bf2f(h));
}

// ---------------------------------------------------------------------------
// Kernel 2a: q/k conv (bf16x3). grid (b 8, y 56), block 256 = 4 waves.
// ---------------------------------------------------------------------------
__global__ __launch_bounds__(256) void conv_qk2(
    const unsigned short* __restrict__ xhi, const unsigned short* __restrict__ xlo,
    const unsigned short* __restrict__ Ahi, const unsigned short* __restrict__ Alo,
    const float* __restrict__ bq, const float* __restrict__ bk,
    unsigned short* __restrict__ qkt_hi, unsigned short* __restrict__ qkt_lo)
{
    __shared__ uint4 sH[3*64*4 + 8];   // +8 pad: col+dx can run to 65 (px>=56 discarded)
    __shared__ uint4 sL[3*64*4 + 8];
    const int b = blockIdx.x, y = blockIdx.y;
    const int t = threadIdx.x;
    const int w = t >> 6, L = t & 63;
    const int ln = L & 15, quad = L >> 4;

    f32x4 acc[4];
#pragma unroll
    for (int nt = 0; nt < 4; nt++) acc[nt] = (f32x4)0.0f;

    uint4 ph[3], pl[3];
#pragma unroll
    for (int i = 0; i < 3; i++) {
        const int idx = t + i*256;
        const int r = idx >> 8, col = (idx >> 2) & 63, c8 = idx & 3;
        const size_t go = ((size_t)((b*58 + y + r)*64 + col))*256 + c8*8;
        ph[i] = *(const uint4*)(xhi + go);
        pl[i] = *(const uint4*)(xlo + go);
    }

    for (int cc = 0; cc < 8; cc++) {
        __syncthreads();
#pragma unroll
        for (int i = 0; i < 3; i++) {
            const int idx = t + i*256;
            const int r = idx >> 8, col = (idx >> 2) & 63, c8 = idx & 3;
            sH[SWZ(r, col, c8)] = ph[i];
            sL[SWZ(r, col, c8)] = pl[i];
        }
        __syncthreads();
        if (cc < 7) {
#pragma unroll
            for (int i = 0; i < 3; i++) {
                const int idx = t + i*256;
                const int r = idx >> 8, col = (idx >> 2) & 63, c8 = idx & 3;
                const size_t go = ((size_t)((b*58 + y + r)*64 + col))*256 + (cc+1)*32 + c8*8;
                ph[i] = *(const uint4*)(xhi + go);
                pl[i] = *(const uint4*)(xlo + go);
            }
        }
#pragma unroll
        for (int s = 0; s < 9; s++) {
            const int dy = s / 3 - 1, dx = s % 3 - 1;
            const size_t aoff = (size_t)(w*16 + ln)*2304 + s*256 + cc*32 + quad*8;
            const short8 ah = *(const short8*)(Ahi + aoff);
            const short8 al = *(const short8*)(Alo + aoff);
            const int r = dy + 1;
#pragma unroll
            for (int nt = 0; nt < 4; nt++) {
                const int col = nt*16 + ln + dx + 1;
                const int i4 = SWZ(r, col, quad);
                const short8 bh = *(const short8*)&sH[i4];
                const short8 bl = *(const short8*)&sL[i4];
                acc[nt] = MFMA16(ah, bh, acc[nt]);
                acc[nt] = MFMA16(ah, bl, acc[nt]);
                acc[nt] = MFMA16(al, bh, acc[nt]);
            }
        }
    }

    // epilogue: C/D col = ln (px), row = quad*4 + r (m-row within wave's 16)
#pragma unroll
    for (int nt = 0; nt < 4; nt++) {
        const int px = nt*16 + ln;
        if (px >= 56) continue;
        const int pix = y*56 + px;
        u16x4 hi4, lo4;
#pragma unroll
        for (int r = 0; r < 4; r++) {
            const int m = w*16 + quad*4 + r;
            const float bias = (m < 32) ? bq[m] : bk[m - 32];
            const float val = acc[nt][r] + bias;
            const unsigned short h = f2bf(val);
            hi4[r] = h;
            lo4[r] = f2bf(val - bf2f(h));
        }
        const size_t o = (size_t)(b*N_ + pix)*64 + w*16 + quad*4;
        *(u16x4*)(qkt_hi + o) = hi4;
        *(u16x4*)(qkt_lo + o) = lo4;
    }
}

// ---------------------------------------------------------------------------
// Kernel 2b: v conv (plain bf16). grid (b 8, y 56, mg 4), block 256 = 4 waves.
// ---------------------------------------------------------------------------
__global__ __launch_bounds__(256) void conv_v2(
    const unsigned short* __restrict__ xhi,
    const unsigned short* __restrict__ Ahi,
    const float* __restrict__ bv,
    unsigned short* __restrict__ vbf)
{
    __shared__ uint4 sH[3*64*4 + 8];
    const int b = blockIdx.x, y = blockIdx.y, mg = blockIdx.z;
    const int t = threadIdx.x;
    const int w = t >> 6, L = t & 63;
    const int ln = L & 15, quad = L >> 4;
    const int m0 = 64 + mg*64 + w*16;   // A row base (v rows start at 64)

    f32x4 acc[4];
#pragma unroll
    for (int nt = 0; nt < 4; nt++) acc[nt] = (f32x4)0.0f;

    uint4 ph[3];
#pragma unroll
    for (int i = 0; i < 3; i++) {
        const int idx = t + i*256;
        const int r = idx >> 8, col = (idx >> 2) & 63, c8 = idx & 3;
        const size_t go = ((size_t)((b*58 + y + r)*64 + col))*256 + c8*8;
        ph[i] = *(const uint4*)(xhi + go);
    }

    for (int cc = 0; cc < 8; cc++) {
        __syncthreads();
#pragma unroll
        for (int i = 0; i < 3; i++) {
            const int idx = t + i*256;
            const int r = idx >> 8, col = (idx >> 2) & 63, c8 = idx & 3;
            sH[SWZ(r, col, c8)] = ph[i];
        }
        __syncthreads();
        if (cc < 7) {
#pragma unroll
            for (int i = 0; i < 3; i++) {
                const int idx = t + i*256;
                const int r = idx >> 8, col = (idx >> 2) & 63, c8 = idx & 3;
                const size_t go = ((size_t)((b*58 + y + r)*64 + col))*256 + (cc+1)*32 + c8*8;
                ph[i] = *(const uint4*)(xhi + go);
            }
        }
#pragma unroll
        for (int s = 0; s < 9; s++) {
            const int dy = s / 3 - 1, dx = s % 3 - 1;
            const size_t aoff = (size_t)(m0 + ln)*2304 + s*256 + cc*32 + quad*8;
            const short8 a = *(const short8*)(Ahi + aoff);
            const int r = dy + 1;
#pragma unroll
            for (int nt = 0; nt < 4; nt++) {
                const int col = nt*16 + ln + dx + 1;
                const short8 bf = *(const short8*)&sH[SWZ(r, col, quad)];
                acc[nt] = MFMA16(a, bf, acc[nt]);
            }
        }
    }

    // epilogue: v channel c = mg*64 + w*16 + quad*4 + r
#pragma unroll
    for (int nt = 0; nt < 4; nt++) {
        const int px = nt*16 + ln;
        if (px >= 56) continue;
        const int pix = y*56 + px;
#pragma unroll
        for (int r = 0; r < 4; r++) {
            const int c = mg*64 + w*16 + quad*4 + r;
            vbf[(size_t)(b*C_ + c)*N_ + pix] = f2bf(acc[nt][r] + bv[c]);
        }
    }
}

// ---------------------------------------------------------------------------
// Kernel 3: fused flash attention, j-split. grid (392, chalf 2, jh 2),
// block 256 = 4 waves. Writes UNNORMALIZED O-partials (bf16) + per-row m,l.
// launch_bounds (256,4): VGPR cap 128 -> NO SPILLS (R7's (256,6) forced
// 40 VGPRs and spilled ~2.3 GB of scratch traffic to HBM).
// ---------------------------------------------------------------------------
__global__ __launch_bounds__(256, 4) void attn_flash3(
    const unsigned short* __restrict__ qkt_hi, const unsigned short* __restrict__ qkt_lo,
    const unsigned short* __restrict__ vbf,
    unsigned short* __restrict__ op0, unsigned short* __restrict__ op1,
    float* __restrict__ mlbase)
{
    __shared__ unsigned short P[2][64*PSTR];   // 19.0 KB
    __shared__ float alphaL[2][64];

    const int bx = blockIdx.x;
    const int b = bx & 7, it = bx >> 3;
    const int chalf = blockIdx.y;
    const int jh = blockIdx.z;
    const int jt0 = jh * 25, njt = 25 - jh;   // 25 / 24 tiles
    const int i_base = it * 64;
    const int t = threadIdx.x;
    const int w = t >> 6, L = t & 63;
    const int ln = L & 15, quad = L >> 4;
    const int l32 = L & 31, h32 = L >> 5;

    const size_t qoff = (size_t)(b*N_ + i_base + w*16 + ln)*64 + quad*8;
    const short8 qh = *(const short8*)(qkt_hi + qoff);
    const short8 ql = *(const short8*)(qkt_lo + qoff);

    float m_run = -INFINITY, l_run = 0.0f;
    f32x16 O0 = (f32x16)0.0f, O1 = (f32x16)0.0f;
    const unsigned short* vrow = vbf + (size_t)(b*C_ + chalf*128 + w*32 + l32) * N_;

    for (int jtl = 0; jtl < njt; jtl++) {
        const int jt = jt0 + jtl;
        const int buf = jtl & 1;

        // ---- V prefetch first (addresses independent of everything) ----
        short8 Va[4];
#pragma unroll
        for (int s = 0; s < 4; s++)
            Va[s] = *(const short8*)(vrow + jt*64 + s*16 + h32*8);

        // ---- S^T phase ----
        f32x4 sacc[4];
#pragma unroll
        for (int tj = 0; tj < 4; tj++) {
            const size_t koff = (size_t)(b*N_ + jt*64 + tj*16 + ln)*64 + 32 + quad*8;
            const short8 kh = *(const short8*)(qkt_hi + koff);
            const short8 kl = *(const short8*)(qkt_lo + koff);
            f32x4 a = (f32x4)0.0f;
            a = MFMA16(kh, qh, a);
            a = MFMA16(kh, ql, a);
            a = MFMA16(kl, qh, a);
            sacc[tj] = a;
        }
        // ---- stats: depth-4 max tree + 2 shuffles ----
        float mt0 = fmaxf(fmaxf(sacc[0][0], sacc[0][1]), fmaxf(sacc[0][2], sacc[0][3]));
        float mt1 = fmaxf(fmaxf(sacc[1][0], sacc[1][1]), fmaxf(sacc[1][2], sacc[1][3]));
        float mt2 = fmaxf(fmaxf(sacc[2][0], sacc[2][1]), fmaxf(sacc[2][2], sacc[2][3]));
        float mt3 = fmaxf(fmaxf(sacc[3][0], sacc[3][1]), fmaxf(sacc[3][2], sacc[3][3]));
        float mx = fmaxf(fmaxf(mt0, mt1), fmaxf(mt2, mt3));
        mx = fmaxf(mx, __shfl_xor(mx, 16));
        mx = fmaxf(mx, __shfl_xor(mx, 32));
        const float m_new = fmaxf(m_run, mx);
        const float alpha = __expf(m_run - m_new);
        m_run = m_new;

        float p[4][4];
#pragma unroll
        for (int tj = 0; tj < 4; tj++)
#pragma unroll
            for (int r = 0; r < 4; r++)
                p[tj][r] = __expf(sacc[tj][r] - m_new);
        float s0 = (p[0][0] + p[0][1]) + (p[0][2] + p[0][3]);
        float s1 = (p[1][0] + p[1][1]) + (p[1][2] + p[1][3]);
        float s2 = (p[2][0] + p[2][1]) + (p[2][2] + p[2][3]);
        float s3 = (p[3][0] + p[3][1]) + (p[3][2] + p[3][3]);
        float ps = (s0 + s1) + (s2 + s3);
        ps += __shfl_xor(ps, 16);
        ps += __shfl_xor(ps, 32);
        l_run = l_run * alpha + ps;

        {
            unsigned short* prow = &P[buf][(w*16 + ln)*PSTR];
#pragma unroll
            for (int tj = 0; tj < 4; tj++) {
                u16x4 pk;
#pragma unroll
                for (int r = 0; r < 4; r++) pk[r] = f2bf(p[tj][r]);
                *(u16x4*)(prow + tj*16 + quad*4) = pk;
            }
        }
        if (quad == 0) alphaL[buf][w*16 + ln] = alpha;

        __syncthreads();   // P[buf] + alphaL[buf] ready

        // ---- PV phase ----
        const float a0 = alphaL[buf][l32];
        const float a1 = alphaL[buf][32 + l32];
        if (__any(a0 != 1.0f || a1 != 1.0f)) {
#pragma unroll
            for (int rg = 0; rg < 16; rg++) { O0[rg] *= a0; O1[rg] *= a1; }
        }
#pragma unroll
        for (int s = 0; s < 4; s++) {
            const short8 B0 = *(const short8*)&P[buf][l32*PSTR + s*16 + h32*8];
            const short8 B1 = *(const short8*)&P[buf][(32 + l32)*PSTR + s*16 + h32*8];
            O0 = MFMA32(Va[s], B0, O0);
            O1 = MFMA32(Va[s], B1, O1);
        }
    }

    // ---- epilogue: raw partials ----
    if (chalf == 0 && quad == 0) {
        const int i = i_base + w*16 + ln;
        mlbase[jh*BN_ + b*N_ + i]       = m_run;
        mlbase[(2 + jh)*BN_ + b*N_ + i] = l_run;
    }
    unsigned short* OP = jh ? op1 : op0;
#pragma unroll
    for (int itile = 0; itile < 2; itile++) {
        const f32x16 Ot = itile ? O1 : O0;
        const int pix = i_base + itile*32 + l32;
#pragma unroll
        for (int reg = 0; reg < 16; reg++) {
            const int c = chalf*128 + w*32 + (reg & 3) + 8*(reg >> 2) + 4*h32;
            OP[(size_t)(b*C_ + c)*N_ + pix] = f2bf(Ot[reg]);
        }
    }
}

// ---------------------------------------------------------------------------
// Kernel 4: combine the two j-half partials + residual.
// grid (392 = b*49, ch2 2), block 256: lane = pix offset (64), t>>6 = c offset.
// ---------------------------------------------------------------------------
__global__ __launch_bounds__(256) void combine(
    const unsigned short* __restrict__ op0, const unsigned short* __restrict__ op1,
    const float* __restrict__ mlbase,
    const float* __restrict__ x, const float* __restrict__ gptr,
    float* __restrict__ out)
{
    const int bid = blockIdx.x;
    const int b = bid / 49, pt = bid - b*49;
    const int ch2 = blockIdx.y;
    const int t = threadIdx.x;
    const int pix = pt*64 + (t & 63);
    const int cofs = t >> 6;

    const float m0 = mlbase[b*N_ + pix];
    const float m1 = mlbase[BN_ + b*N_ + pix];
    const float l0 = mlbase[2*BN_ + b*N_ + pix];
    const float l1 = mlbase[3*BN_ + b*N_ + pix];
    const float mm = fmaxf(m0, m1);
    const float a0 = __expf(m0 - mm), a1 = __expf(m1 - mm);
    const float gamma = gptr[0];
    const float inv = gamma / (a0*l0 + a1*l1);
    const float c0 = a0 * inv, c1 = a1 * inv;

    for (int ci = 0; ci < 32; ci++) {
        const int c = ch2*128 + cofs + ci*4;
        const size_t idx = (size_t)(b*C_ + c)*N_ + pix;
        const float o = c0 * bf2f(op0[idx]) + c1 * bf2f(op1[idx]);
        out[idx] = x[idx] + o;
    }
}

// ---------------------------------------------------------------------------
extern "C" void kernel_launch(void* const* d_in, const int* in_sizes, int n_in,
                              void* d_out, int out_size, void* d_ws, size_t ws_size,
                              hipStream_t stream)
{
    (void)in_sizes; (void)n_in; (void)out_size; (void)ws_size;
    const float* x  = (const float*)d_in[0];
    const float* wq = (const float*)d_in[1];
    const float* bq = (const float*)d_in[2];
    const float* wk = (const float*)d_in[3];
    const float* bk = (const float*)d_in[4];
    const float* wv = (const float*)d_in[5];
    const float* bv = (const float*)d_in[6];
    const float* gm = (const float*)d_in[7];
    float* out = (float*)d_out;

    unsigned short* u = (unsigned short*)d_ws;
    unsigned short* xhi = u;                      // conv input; later O-partial jh=0
    unsigned short* xlo = u + XT_ELEMS;           // conv input; later O-partial jh=1
    unsigned short* Ahi = u + AHI_OFF;            // weights; first 400KB later m/l
    unsigned short* Alo = u + ALO_OFF;
    unsigned short* qkt_hi = u + QKT_HI_OFF;
    unsigned short* qkt_lo = u + QKT_LO_OFF;
    unsigned short* vbf = u + VBF_OFF;
    float* mlbase = (float*)Ahi;                  // 4 * B*N floats = 401 KB

    hipLaunchKernelGGL(zero_pads, dim3(1024), dim3(256), 0, stream,
                       (uint4*)d_ws, (2*XT_ELEMS*2)/16);
    hipLaunchKernelGGL(prep_x, dim3(4, 56, 8), dim3(256), 0, stream, x, xhi, xlo);
    hipLaunchKernelGGL(prep_w, dim3(2880), dim3(256), 0, stream, wq, wk, wv, Ahi, Alo);
    hipLaunchKernelGGL(conv_qk2, dim3(8, 56), dim3(256), 0, stream,
                       xhi, xlo, Ahi, Alo, bq, bk, qkt_hi, qkt_lo);
    hipLaunchKernelGGL(conv_v2, dim3(8, 56, 4), dim3(256), 0, stream,
                       xhi, Ahi, bv, vbf);
    hipLaunchKernelGGL(attn_flash3, dim3(49*8, 2, 2), dim3(256), 0, stream,
                       qkt_hi, qkt_lo, vbf, xhi, xlo, mlbase);
    hipLaunchKernelGGL(combine, dim3(392, 2), dim3(256), 0, stream,
                       xhi, xlo, mlbase, x, gm, out);
}